// Round 5
// baseline (199.338 us; speedup 1.0000x reference)
//
#include <hip/hip_runtime.h>
#include <cstdint>

typedef unsigned short u16;
typedef __bf16 bf16x8 __attribute__((ext_vector_type(8)));
typedef float f32x16 __attribute__((ext_vector_type(16)));

#define NB 8192          // batch rows
#define HD 512           // hidden
#define KD 1024          // IN + H
#define ND 2048          // 4H (physical, column-reordered)
#define HY_OFF (NB * HD) // offset of cy in d_out
#define NT 32            // K-tiles of BK=32

// ---------- helpers ----------
__device__ __forceinline__ u16 f2bf(float f) {
  unsigned u = __float_as_uint(f);
  u += 0x7FFFu + ((u >> 16) & 1u);          // round-to-nearest-even bf16
  return (u16)(u >> 16);
}
__device__ __forceinline__ float bf2f(u16 h) {
  return __uint_as_float(((unsigned)h) << 16);
}
__device__ __forceinline__ void atomicMaxF(float* a, float v) {
  if (v >= 0.f) atomicMax((int*)a, __float_as_int(v));
  else          atomicMin((unsigned int*)a, __float_as_uint(v));
}
__device__ __forceinline__ float fq_u(float x) {           // unsigned 8-bit fake-quant
  float xc = fminf(fmaxf(x, 0.0f), 1.0f);
  return rintf(xc * 256.0f) * (1.0f / 256.0f);
}
__device__ __forceinline__ float fq_s(float x) {           // signed 8-bit fake-quant
  const float lim = 1.0f - 1.0f / 128.0f;
  float xc = fminf(fmaxf(x, -lim), lim);
  return rintf(xc * 128.0f) * (1.0f / 128.0f);
}
__device__ __forceinline__ float sigm(float x) { return 1.0f / (1.0f + expf(-x)); }

__device__ __forceinline__ void gload_lds16(const u16* g, u16* l) {
  __builtin_amdgcn_global_load_lds(
      (const __attribute__((address_space(1))) void*)g,
      (__attribute__((address_space(3))) void*)l, 16, 0, 0);
}

// ---------- max reductions (4 tensors -> maxes[0..3]) ----------
__global__ __launch_bounds__(256) void k_prep_max(
    const float* __restrict__ w_ih, const float* __restrict__ w_hh,
    const float* __restrict__ b_ih, const float* __restrict__ b_hh,
    float* __restrict__ maxes) {
  int bid = blockIdx.x;
  const float* src; int slot, base;
  if (bid < 1024)      { src = w_ih; slot = 0; base = bid * 1024; }
  else if (bid < 2048) { src = w_hh; slot = 1; base = (bid - 1024) * 1024; }
  else if (bid < 2050) { src = b_ih; slot = 2; base = (bid - 2048) * 1024; }
  else                 { src = b_hh; slot = 3; base = (bid - 2050) * 1024; }
  float m = -INFINITY;
  for (int i = threadIdx.x; i < 1024; i += 256) m = fmaxf(m, src[base + i]);
  for (int k = 1; k < 64; k <<= 1) m = fmaxf(m, __shfl_xor(m, k, 64));
  __shared__ float sm[4];
  if ((threadIdx.x & 63) == 0) sm[threadIdx.x >> 6] = m;
  __syncthreads();
  if (threadIdx.x == 0) {
    m = fmaxf(fmaxf(sm[0], sm[1]), fmaxf(sm[2], sm[3]));
    atomicMaxF(&maxes[slot], m);
  }
}

// ---------- fused prep: split X hi/lo + build W hi/lo (coalesced) + bias ----------
// blocks [0,2048): split X ; [2048,2176): W 16-col groups ; [2176,2184): bias
// W physical j bits: [10:8]=bn, [7]=nh, [6:5]=wc, [4:0]=col-in-32 (lane)
// gate g = 2*nh + bit4 ; h-block hb = bn*4 + wc ; logical col = g*512 + hb*16 + j[3:0]
__global__ __launch_bounds__(256) void k_prep_build(
    const float* __restrict__ input, const float* __restrict__ hx,
    const float* __restrict__ w_ih, const float* __restrict__ w_hh,
    const float* __restrict__ n_ih, const float* __restrict__ n_hh,
    const float* __restrict__ b_ih, const float* __restrict__ b_hh,
    const float* __restrict__ nb_ih, const float* __restrict__ nb_hh,
    const float* __restrict__ maxes,
    u16* __restrict__ Xhi, u16* __restrict__ Xlo,
    u16* __restrict__ Whi, u16* __restrict__ Wlo,
    float* __restrict__ biasC) {
  const int bid = blockIdx.x;
  if (bid < 2048) {
    const int total4 = NB * KD / 4;
    for (int e4 = bid * 256 + threadIdx.x; e4 < total4; e4 += 2048 * 256) {
      int row = e4 >> 8;
      int c4  = e4 & 255;
      float4 v = (c4 < 128)
          ? reinterpret_cast<const float4*>(input)[row * 128 + c4]
          : reinterpret_cast<const float4*>(hx)[row * 128 + (c4 - 128)];
      float xs[4] = {v.x, v.y, v.z, v.w};
      ushort4 hi, lo;
      u16 h0 = f2bf(xs[0]); u16 l0 = f2bf(xs[0] - bf2f(h0));
      u16 h1 = f2bf(xs[1]); u16 l1 = f2bf(xs[1] - bf2f(h1));
      u16 h2 = f2bf(xs[2]); u16 l2 = f2bf(xs[2] - bf2f(h2));
      u16 h3 = f2bf(xs[3]); u16 l3 = f2bf(xs[3] - bf2f(h3));
      hi.x = h0; hi.y = h1; hi.z = h2; hi.w = h3;
      lo.x = l0; lo.y = l1; lo.z = l2; lo.w = l3;
      reinterpret_cast<ushort4*>(Xhi)[e4] = hi;
      reinterpret_cast<ushort4*>(Xlo)[e4] = lo;
    }
  } else if (bid < 2176) {
    // 16 physical cols j0..j0+15 (one lane-group) = 16 consecutive logical cols
    __shared__ float nT[1024][17];   // padded
    const int w  = bid - 2048;
    const int j0 = w * 16;
    const int g  = ((j0 >> 7) & 1) * 2 + ((j0 >> 4) & 1);
    const int hb = ((j0 >> 8) << 2) | ((j0 >> 5) & 3);
    const int col0 = g * 512 + (hb << 4);
    {  // stage noise[k][col0..col0+16) -> nT, coalesced
      const int cl = threadIdx.x & 15;
      const int kr = threadIdx.x >> 4;
#pragma unroll 4
      for (int i = 0; i < 64; ++i) {
        const int k = kr + 16 * i;
        nT[k][cl] = (k < 512) ? n_ih[k * ND + col0 + cl]
                              : n_hh[(k - 512) * ND + col0 + cl];
      }
    }
    __syncthreads();
    const float s_ih = maxes[0] * 0.1f, s_hh = maxes[1] * 0.1f;
    const int c  = threadIdx.x >> 4;       // col 0..15
    const int kl = threadIdx.x & 15;
    const int colL = col0 + c;
    const int j = j0 + c;
#pragma unroll 4
    for (int kk = 0; kk < 16; ++kk) {
      const int k = kk * 64 + kl * 4;
      float4 wv; float s;
      if (k < 512) {
        wv = reinterpret_cast<const float4*>(w_ih)[(colL * 512 + k) >> 2];
        s = s_ih;
      } else {
        wv = reinterpret_cast<const float4*>(w_hh)[(colL * 512 + k - 512) >> 2];
        s = s_hh;
      }
      float xs[4] = {wv.x + nT[k + 0][c] * s, wv.y + nT[k + 1][c] * s,
                     wv.z + nT[k + 2][c] * s, wv.w + nT[k + 3][c] * s};
      ushort4 hi, lo;
      u16 h0 = f2bf(xs[0]); u16 l0 = f2bf(xs[0] - bf2f(h0));
      u16 h1 = f2bf(xs[1]); u16 l1 = f2bf(xs[1] - bf2f(h1));
      u16 h2 = f2bf(xs[2]); u16 l2 = f2bf(xs[2] - bf2f(h2));
      u16 h3 = f2bf(xs[3]); u16 l3 = f2bf(xs[3] - bf2f(h3));
      hi.x = h0; hi.y = h1; hi.z = h2; hi.w = h3;
      lo.x = l0; lo.y = l1; lo.z = l2; lo.w = l3;
      reinterpret_cast<ushort4*>(Whi)[(j * KD + k) >> 2] = hi;
      reinterpret_cast<ushort4*>(Wlo)[(j * KD + k) >> 2] = lo;
    }
  } else {
    int j = (bid - 2176) * 256 + threadIdx.x;
    if (j < ND) {
      int g  = ((j >> 7) & 1) * 2 + ((j >> 4) & 1);
      int hb = ((j >> 8) << 2) | ((j >> 5) & 3);
      int col = g * 512 + (hb << 4) + (j & 15);
      biasC[j] = b_ih[col] + nb_ih[col] * (maxes[2] * 0.1f)
               + b_hh[col] + nb_hh[col] * (maxes[3] * 0.1f);
    }
  }
}

// ---------- GEMM 256x256-tile, BK=32, 32x32x16 MFMA, 4 phases/tile ----------
// grid 256; 512 threads (8 waves, 2x4); LDS 128 KiB = 2 slots x 4 bufs x 16 KB.
// Same LDS layout/swizzle/staging as the passing r3/r4 kernels; only the frag
// reads, MFMA shape, and epilogue change. Sound vmcnt ledger: waits 4/4/-/2.
__global__ __launch_bounds__(512, 2) void k_gemm_lstm(
    const u16* __restrict__ Xhi, const u16* __restrict__ Xlo,
    const u16* __restrict__ Whi, const u16* __restrict__ Wlo,
    const float* __restrict__ biasC, const float* __restrict__ cx,
    float* __restrict__ out) {
  __shared__ u16 L[2][4][8192];   // [slot][Ahi,Alo,Bhi,Blo][128 ldsrows x 64 u16]
  const int tid  = threadIdx.x;
  const int lane = tid & 63, wid = tid >> 6;
  const int wr = wid >> 2, wc = wid & 3;       // 2 x 4 waves
  // XCD-region map: xcd = blk%8 owns an 8bm x 4bn region (bijective)
  const int xcd = blockIdx.x & 7, tt = blockIdx.x >> 3;
  const int bm = ((xcd >> 1) << 3) | (tt & 7);   // 0..31
  const int bn = ((xcd & 1) << 2) | (tt >> 3);   // 0..7
  const int mbase = bm * 256, nbase = bn * 256;

  // staging consts: lane l -> ldsrow (l>>3), lds chunk l&7, src chunk (l&7)^(l>>3)
  const int l8 = lane >> 3, l7 = lane & 7;
  const int csrc  = l7 ^ l8;
  const int srow  = wid * 16 + 2 * l8 + (csrc >> 2);  // global row offset in panel
  const int skoff = (csrc & 3) * 8;                   // k offset (u16)
  const int sdst  = wid * 512;                        // + HALF*4096 (u16)

  // 32x32x16 frag-read consts: global row = rb + (lane&31), k = ks*16 + hi32*8
  const int l31 = lane & 31, hi32 = lane >> 5;
  const int lh  = l31 >> 1;                                 // ldsrow offset
  const int cb0 = (((lane & 1) << 2) | hi32) ^ (lh & 7);    // swizzled chunk, ks=0
  // ks=1 chunk = cb0 ^ 2

  f32x16 acc[4][2] = {};    // [m = mh*2+m2][nh]
  bf16x8 afr[2][2][2];      // [m2][ks][hi/lo]
  bf16x8 bfr[2][2][2];      // [nh][ks][hi/lo], nh0 lives across ph0..ph3

#define STAGE(V, SLOT, BUF, HALF)                                             \
  {                                                                           \
    const u16* arr_ = (BUF) == 0 ? Xhi : (BUF) == 1 ? Xlo                     \
                      : (BUF) == 2 ? Whi : Wlo;                               \
    const int gb_ = ((BUF) < 2 ? mbase : nbase) + (HALF) * 128 + srow;        \
    gload_lds16(arr_ + (size_t)gb_ * KD + (V) * 32 + skoff,                   \
                &L[(SLOT)][(BUF)][(HALF) * 4096 + sdst]);                     \
  }

#define PH32(S, MH, NH, LOADA, LOADB, STAGE_CODE, WAIT_CODE)                  \
  {                                                                           \
    if (LOADA) {                                                              \
      _Pragma("unroll") for (int m2 = 0; m2 < 2; ++m2)                        \
        _Pragma("unroll") for (int ks = 0; ks < 2; ++ks) {                    \
          const int ao = (MH) * 4096 + (wr * 32 + m2 * 16 + lh) * 64          \
                         + (cb0 ^ (ks << 1)) * 8;                             \
          afr[m2][ks][0] = *reinterpret_cast<const bf16x8*>(&L[S][0][ao]);    \
          afr[m2][ks][1] = *reinterpret_cast<const bf16x8*>(&L[S][1][ao]);    \
        }                                                                     \
    }                                                                         \
    if (LOADB) {                                                              \
      _Pragma("unroll") for (int ks = 0; ks < 2; ++ks) {                      \
        const int bo = (NH) * 4096 + (wc * 16 + lh) * 64                      \
                       + (cb0 ^ (ks << 1)) * 8;                               \
        bfr[(NH)][ks][0] = *reinterpret_cast<const bf16x8*>(&L[S][2][bo]);    \
        bfr[(NH)][ks][1] = *reinterpret_cast<const bf16x8*>(&L[S][3][bo]);    \
      }                                                                       \
    }                                                                         \
    STAGE_CODE;                                                               \
    WAIT_CODE;                                                                \
    __builtin_amdgcn_s_barrier();                                             \
    __builtin_amdgcn_s_setprio(1);                                            \
    _Pragma("unroll") for (int t = 0; t < 3; ++t)                             \
      _Pragma("unroll") for (int ks = 0; ks < 2; ++ks)                        \
        _Pragma("unroll") for (int m2 = 0; m2 < 2; ++m2) {                    \
          f32x16* ac = &acc[(MH) * 2 + m2][NH];                               \
          *ac = __builtin_amdgcn_mfma_f32_32x32x16_bf16(                      \
              afr[m2][ks][t == 1], bfr[(NH)][ks][t == 2], *ac, 0, 0, 0);      \
        }                                                                     \
    __builtin_amdgcn_s_setprio(0);                                            \
    __builtin_amdgcn_s_barrier();                                             \
  }

#define V4 asm volatile("s_waitcnt vmcnt(4)" ::: "memory")
#define V2 asm volatile("s_waitcnt vmcnt(2)" ::: "memory")

  // TILE: 4 phases (mh,nh) = (0,0),(0,1),(1,1),(1,0); stages tile U+1 into S^1.
  // Event order per tile: Ah0,Al0 | Bh0,Bl0 | Bh1,Bl1 | Ah1,Al1. Waits 4/4/-/2.
#define TILE(U, S)                                                            \
  PH32(S, 0, 0, 1, 1,                                                         \
       { STAGE((U) + 1, (S) ^ 1, 0, 0); STAGE((U) + 1, (S) ^ 1, 1, 0); }, V4) \
  PH32(S, 0, 1, 0, 1,                                                         \
       { STAGE((U) + 1, (S) ^ 1, 2, 0); STAGE((U) + 1, (S) ^ 1, 3, 0); }, V4) \
  PH32(S, 1, 1, 1, 0,                                                         \
       { STAGE((U) + 1, (S) ^ 1, 2, 1); STAGE((U) + 1, (S) ^ 1, 3, 1); }, )   \
  PH32(S, 1, 0, 0, 0,                                                         \
       { STAGE((U) + 1, (S) ^ 1, 0, 1); STAGE((U) + 1, (S) ^ 1, 1, 1); }, V2)

  // prologue: stage tile 0 in event order, guarantee first 6 before use
  STAGE(0, 0, 0, 0); STAGE(0, 0, 1, 0);
  STAGE(0, 0, 2, 0); STAGE(0, 0, 3, 0);
  STAGE(0, 0, 2, 1); STAGE(0, 0, 3, 1);
  STAGE(0, 0, 0, 1); STAGE(0, 0, 1, 1);
  V2;
  __builtin_amdgcn_s_barrier();

  for (int u = 0; u < NT - 2; u += 2) {
    TILE(u, 0)
    TILE(u + 1, 1)
  }
  TILE(NT - 2, 0)
  // peeled tile 31 (slot 1): no staging; drain A-h1 before ph2 reads it
  PH32(1, 0, 0, 1, 1, , )
  PH32(1, 0, 1, 0, 1, , asm volatile("s_waitcnt vmcnt(0)" ::: "memory"))
  PH32(1, 1, 1, 1, 0, , )
  PH32(1, 1, 0, 0, 0, , )

#undef TILE
#undef V4
#undef V2
#undef PH32
#undef STAGE

  // ---------- fused quantized-LSTM epilogue ----------
  // C/D (32x32): col = lane&31, row = (r&3) + 8*(r>>2) + 4*hi32.
  // gate g = 2*nh + ((lane>>4)&1); lane^16 holds the complementary gate pair.
  const int b = (lane >> 4) & 1;
  const int h = (bn * 4 + wc) * 16 + (lane & 15);
  const float bias0 = biasC[nbase + wc * 32 + l31];         // nh=0 col
  const float bias1 = biasC[nbase + 128 + wc * 32 + l31];   // nh=1 col
#pragma unroll
  for (int m = 0; m < 4; ++m) {
#pragma unroll
    for (int r = 0; r < 16; ++r) {
      const int row = mbase + (m >> 1) * 128 + wr * 64 + (m & 1) * 32
                      + (r & 3) + 8 * (r >> 2) + 4 * hi32;
      const float v0 = acc[m][0][r] + bias0;   // gate b   (in if b=0, forget if b=1)
      const float v1 = acc[m][1][r] + bias1;   // gate 2+b (cell if b=0, out if b=1)
      const float w0 = __shfl_xor(v0, 16, 64);
      const float w1 = __shfl_xor(v1, 16, 64);
      const float gi = b ? w0 : v0;
      const float gf = b ? v0 : w0;
      const float gc = b ? w1 : v1;
      const float go = b ? v1 : w1;
      const float ig = fq_u(sigm(gi));
      const float fg = fq_u(sigm(gf));
      const float cg = fq_s(tanhf(gc));
      const float og = fq_u(sigm(go));
      const float cxv = cx[(size_t)row * HD + h];
      const float t1 = fq_s(fg * cxv);
      const float t2 = fq_s(ig * cg);
      const float cyv = fq_s((t1 + t2) * 0.5f);
      const float hyv = fq_s(og * fq_s(tanhf(cyv * 2.0f)));
      if (b) out[HY_OFF + (size_t)row * HD + h] = cyv;
      else   out[(size_t)row * HD + h] = hyv;
    }
  }
}

// ---------- launch ----------
extern "C" void kernel_launch(void* const* d_in, const int* in_sizes, int n_in,
                              void* d_out, int out_size, void* d_ws, size_t ws_size,
                              hipStream_t stream) {
  const float* input = (const float*)d_in[0];
  const float* hx    = (const float*)d_in[1];
  const float* cx    = (const float*)d_in[2];
  const float* w_ih  = (const float*)d_in[3];
  const float* w_hh  = (const float*)d_in[4];
  const float* b_ih  = (const float*)d_in[5];
  const float* b_hh  = (const float*)d_in[6];
  const float* n_ih  = (const float*)d_in[7];
  const float* n_hh  = (const float*)d_in[8];
  const float* nb_ih = (const float*)d_in[9];
  const float* nb_hh = (const float*)d_in[10];
  float* out = (float*)d_out;

  char* ws = (char*)d_ws;
  float* maxes = (float*)ws;                                   // 16 B (+pad to 256)
  u16* Xhi = (u16*)(ws + 256);                                 // 16 MB
  u16* Xlo = (u16*)(ws + 256 + 16777216);                      // 16 MB
  u16* Whi = (u16*)(ws + 256 + 2 * 16777216);                  // 4 MB
  u16* Wlo = (u16*)(ws + 256 + 2 * 16777216 + 4194304);        // 4 MB
  float* biasC = (float*)(ws + 256 + 2 * 16777216 + 2 * 4194304); // 8 KB

  hipMemsetAsync(maxes, 0xFF, 16, stream);  // -NaN sentinel; atomic lattice fixes it
  hipLaunchKernelGGL(k_prep_max, dim3(2052), dim3(256), 0, stream,
                     w_ih, w_hh, b_ih, b_hh, maxes);
  hipLaunchKernelGGL(k_prep_build, dim3(2184), dim3(256), 0, stream,
                     input, hx, w_ih, w_hh, n_ih, n_hh, b_ih, b_hh,
                     nb_ih, nb_hh, maxes, Xhi, Xlo, Whi, Wlo, biasC);
  hipLaunchKernelGGL(k_gemm_lstm, dim3(256), dim3(512), 0, stream,
                     Xhi, Xlo, Whi, Wlo, biasC, cx, out);
}

// Round 6
// 146.365 us; speedup vs baseline: 1.3619x; 1.3619x over previous
//
#include <hip/hip_runtime.h>
#include <cstdint>

typedef unsigned short u16;
typedef __bf16 bf16x8 __attribute__((ext_vector_type(8)));
typedef float f32x4 __attribute__((ext_vector_type(4)));

#define NB 8192          // batch rows
#define HD 512           // hidden
#define KD 1024          // IN + H
#define ND 2048          // 4H (physical, column-reordered)
#define HY_OFF (NB * HD) // offset of cy in d_out
#define NT 32            // K-tiles of BK=32

// ---------- helpers ----------
__device__ __forceinline__ u16 f2bf(float f) {
  unsigned u = __float_as_uint(f);
  u += 0x7FFFu + ((u >> 16) & 1u);          // round-to-nearest-even bf16
  return (u16)(u >> 16);
}
__device__ __forceinline__ float bf2f(u16 h) {
  return __uint_as_float(((unsigned)h) << 16);
}
__device__ __forceinline__ void atomicMaxF(float* a, float v) {
  if (v >= 0.f) atomicMax((int*)a, __float_as_int(v));
  else          atomicMin((unsigned int*)a, __float_as_uint(v));
}
__device__ __forceinline__ float fq_u(float x) {           // unsigned 8-bit fake-quant
  float xc = fminf(fmaxf(x, 0.0f), 1.0f);
  return rintf(xc * 256.0f) * (1.0f / 256.0f);
}
__device__ __forceinline__ float fq_s(float x) {           // signed 8-bit fake-quant
  const float lim = 1.0f - 1.0f / 128.0f;
  float xc = fminf(fmaxf(x, -lim), lim);
  return rintf(xc * 128.0f) * (1.0f / 128.0f);
}
__device__ __forceinline__ float sigm(float x) { return 1.0f / (1.0f + expf(-x)); }

__device__ __forceinline__ void gload_lds16(const u16* g, u16* l) {
  __builtin_amdgcn_global_load_lds(
      (const __attribute__((address_space(1))) void*)g,
      (__attribute__((address_space(3))) void*)l, 16, 0, 0);
}

// ---------- max reductions (4 tensors -> maxes[0..3]) ----------
__global__ __launch_bounds__(256) void k_prep_max(
    const float* __restrict__ w_ih, const float* __restrict__ w_hh,
    const float* __restrict__ b_ih, const float* __restrict__ b_hh,
    float* __restrict__ maxes) {
  int bid = blockIdx.x;
  const float* src; int slot, base;
  if (bid < 1024)      { src = w_ih; slot = 0; base = bid * 1024; }
  else if (bid < 2048) { src = w_hh; slot = 1; base = (bid - 1024) * 1024; }
  else if (bid < 2050) { src = b_ih; slot = 2; base = (bid - 2048) * 1024; }
  else                 { src = b_hh; slot = 3; base = (bid - 2050) * 1024; }
  float m = -INFINITY;
  for (int i = threadIdx.x; i < 1024; i += 256) m = fmaxf(m, src[base + i]);
  for (int k = 1; k < 64; k <<= 1) m = fmaxf(m, __shfl_xor(m, k, 64));
  __shared__ float sm[4];
  if ((threadIdx.x & 63) == 0) sm[threadIdx.x >> 6] = m;
  __syncthreads();
  if (threadIdx.x == 0) {
    m = fmaxf(fmaxf(sm[0], sm[1]), fmaxf(sm[2], sm[3]));
    atomicMaxF(&maxes[slot], m);
  }
}

// ---------- fused prep: split X hi/lo + build W hi/lo (coalesced) + bias ----------
// blocks [0,2048): split X ; [2048,2560): W (16 cols x 256 k each) ; [2560,2568): bias
// W physical j bits: [10:8]=bn, [7]=nh, [6:5]=wc, [4]=n2, [3:0]=lane
// gate g = 2*nh + n2 ; h-block hb = bn*4 + wc ; logical col = g*512 + hb*16 + j[3:0]
__global__ __launch_bounds__(256) void k_prep_build(
    const float* __restrict__ input, const float* __restrict__ hx,
    const float* __restrict__ w_ih, const float* __restrict__ w_hh,
    const float* __restrict__ n_ih, const float* __restrict__ n_hh,
    const float* __restrict__ b_ih, const float* __restrict__ b_hh,
    const float* __restrict__ nb_ih, const float* __restrict__ nb_hh,
    const float* __restrict__ maxes,
    u16* __restrict__ Xhi, u16* __restrict__ Xlo,
    u16* __restrict__ Whi, u16* __restrict__ Wlo,
    float* __restrict__ biasC) {
  const int bid = blockIdx.x;
  if (bid < 2048) {
    const int total4 = NB * KD / 4;
    for (int e4 = bid * 256 + threadIdx.x; e4 < total4; e4 += 2048 * 256) {
      int row = e4 >> 8;
      int c4  = e4 & 255;
      float4 v = (c4 < 128)
          ? reinterpret_cast<const float4*>(input)[row * 128 + c4]
          : reinterpret_cast<const float4*>(hx)[row * 128 + (c4 - 128)];
      float xs[4] = {v.x, v.y, v.z, v.w};
      ushort4 hi, lo;
      u16 h0 = f2bf(xs[0]); u16 l0 = f2bf(xs[0] - bf2f(h0));
      u16 h1 = f2bf(xs[1]); u16 l1 = f2bf(xs[1] - bf2f(h1));
      u16 h2 = f2bf(xs[2]); u16 l2 = f2bf(xs[2] - bf2f(h2));
      u16 h3 = f2bf(xs[3]); u16 l3 = f2bf(xs[3] - bf2f(h3));
      hi.x = h0; hi.y = h1; hi.z = h2; hi.w = h3;
      lo.x = l0; lo.y = l1; lo.z = l2; lo.w = l3;
      reinterpret_cast<ushort4*>(Xhi)[e4] = hi;
      reinterpret_cast<ushort4*>(Xlo)[e4] = lo;
    }
  } else if (bid < 2560) {
    // one block: 16 physical cols (one lane-group) x 256 k-rows
    __shared__ float nT[256][17];   // padded transpose buffer (17 KB)
    const int w  = bid - 2048;      // 0..511
    const int cg = w >> 2, kb = w & 3;
    const int j0 = cg * 16;
    const int g  = ((j0 >> 7) & 1) * 2 + ((j0 >> 4) & 1);
    const int hb = ((j0 >> 8) << 2) | ((j0 >> 5) & 3);
    const int col0 = g * 512 + (hb << 4);
    const int k0 = kb * 256;
    {  // stage noise[k0..k0+256)[col0..col0+16) -> nT, coalesced
      const int cl = threadIdx.x & 15;
      const int kr = threadIdx.x >> 4;
#pragma unroll 4
      for (int i = 0; i < 16; ++i) {
        const int k = k0 + kr + 16 * i;
        nT[kr + 16 * i][cl] = (k < 512) ? n_ih[k * ND + col0 + cl]
                                        : n_hh[(k - 512) * ND + col0 + cl];
      }
    }
    __syncthreads();
    const float s_ih = maxes[0] * 0.1f, s_hh = maxes[1] * 0.1f;
    const int c  = threadIdx.x >> 4;       // col 0..15
    const int kl = threadIdx.x & 15;
    const int colL = col0 + c;
    const int j = j0 + c;
#pragma unroll
    for (int kk = 0; kk < 4; ++kk) {
      const int k = k0 + kk * 64 + kl * 4;
      float4 wv; float s;
      if (k < 512) {
        wv = reinterpret_cast<const float4*>(w_ih)[(colL * 512 + k) >> 2];
        s = s_ih;
      } else {
        wv = reinterpret_cast<const float4*>(w_hh)[(colL * 512 + k - 512) >> 2];
        s = s_hh;
      }
      const int kt = k - k0;
      float xs[4] = {wv.x + nT[kt + 0][c] * s, wv.y + nT[kt + 1][c] * s,
                     wv.z + nT[kt + 2][c] * s, wv.w + nT[kt + 3][c] * s};
      ushort4 hi, lo;
      u16 h0 = f2bf(xs[0]); u16 l0 = f2bf(xs[0] - bf2f(h0));
      u16 h1 = f2bf(xs[1]); u16 l1 = f2bf(xs[1] - bf2f(h1));
      u16 h2 = f2bf(xs[2]); u16 l2 = f2bf(xs[2] - bf2f(h2));
      u16 h3 = f2bf(xs[3]); u16 l3 = f2bf(xs[3] - bf2f(h3));
      hi.x = h0; hi.y = h1; hi.z = h2; hi.w = h3;
      lo.x = l0; lo.y = l1; lo.z = l2; lo.w = l3;
      reinterpret_cast<ushort4*>(Whi)[(j * KD + k) >> 2] = hi;
      reinterpret_cast<ushort4*>(Wlo)[(j * KD + k) >> 2] = lo;
    }
  } else {
    int j = (bid - 2560) * 256 + threadIdx.x;
    if (j < ND) {
      int g  = ((j >> 7) & 1) * 2 + ((j >> 4) & 1);
      int hb = ((j >> 8) << 2) | ((j >> 5) & 3);
      int col = g * 512 + (hb << 4) + (j & 15);
      biasC[j] = b_ih[col] + nb_ih[col] * (maxes[2] * 0.1f)
               + b_hh[col] + nb_hh[col] * (maxes[3] * 0.1f);
    }
  }
}

// ---------- GEMM 256x256-tile, BK=32 unified, 4 phases/tile, deep-stagger ----------
// grid 256; 512 threads (8 waves, 2x4); LDS 128 KiB = 2 slots x 4 bufs x 16 KB.
// Stage calendar (strict barrier-separated WAR, single vmcnt(6)/tile):
//   ph0(u): stage aH1(u+1) -> slot s^1   [overwrites aH1(u-1), dead since ph2(u-1)]
//   ph1(u): stage aH0(u+2) -> slot s     [aH0(u) dead since ph0(u)]
//   ph2(u): stage bH0(u+2) -> slot s     [bH0(u) dead since ph0(u)]
//   ph3(u): stage bH1(u+2) -> slot s     [bH1(u) dead since ph1(u)]; vmcnt(6)
// vmcnt(6) leaves {aH0,bH0,bH1}(u+2) in flight; guarantees all of tile u+1 landed,
// every waited-on load issued >=3 phases earlier.
__global__ __launch_bounds__(512, 2) void k_gemm_lstm(
    const u16* __restrict__ Xhi, const u16* __restrict__ Xlo,
    const u16* __restrict__ Whi, const u16* __restrict__ Wlo,
    const float* __restrict__ biasC, const float* __restrict__ cx,
    float* __restrict__ out) {
  __shared__ u16 L[2][4][8192];   // [slot][Ahi,Alo,Bhi,Blo][128 ldsrows x 64 u16]
  const int tid  = threadIdx.x;
  const int lane = tid & 63, wid = tid >> 6;
  const int wr = wid >> 2, wc = wid & 3;       // 2 x 4 waves
  const int lr = lane & 15, lg = lane >> 4;
  // XCD-region map: xcd = blk%8 owns an 8bm x 4bn region (bijective)
  const int xcd = blockIdx.x & 7, tt = blockIdx.x >> 3;
  const int bm = ((xcd >> 1) << 3) | (tt & 7);   // 0..31
  const int bn = ((xcd & 1) << 2) | (tt >> 3);   // 0..7
  const int mbase = bm * 256, nbase = bn * 256;

  // staging consts: lane l -> ldsrow (l>>3), lds chunk l&7, src chunk (l&7)^(l>>3)
  const int l8 = lane >> 3, l7 = lane & 7;
  const int csrc  = l7 ^ l8;
  const int srow  = wid * 16 + 2 * l8 + (csrc >> 2);  // global row offset in panel
  const int skoff = (csrc & 3) * 8;                   // k offset (u16)
  const int sdst  = wid * 512;                        // + HALF*4096 (u16)

  // frag-read per-thread swizzled offset (u16): row pair + chunk XOR
  const int fro = (lr >> 1) * 64 + ((((lr & 1) << 2) | lg) ^ ((lr >> 1) & 7)) * 8;

  f32x4 acc[8][4] = {};     // [mh*4+m2][gate = 2*nh+n2]
  bf16x8 afr[4][2];         // [m2][hi/lo]
  bf16x8 bfr[2][2][2];      // [nh][n2][hi/lo], nh0 lives ph0..ph3

#define STAGE(V, SLOT, BUF, HALF)                                             \
  {                                                                           \
    const u16* arr_ = (BUF) == 0 ? Xhi : (BUF) == 1 ? Xlo                     \
                      : (BUF) == 2 ? Whi : Wlo;                               \
    const int gb_ = ((BUF) < 2 ? mbase : nbase) + (HALF) * 128 + srow;        \
    gload_lds16(arr_ + (size_t)gb_ * KD + (V) * 32 + skoff,                   \
                &L[(SLOT)][(BUF)][(HALF) * 4096 + sdst]);                     \
  }

#define PH(S, MH, NH, LOADA, LOADB, STAGE_CODE, WAIT_CODE)                    \
  {                                                                           \
    if (LOADA) {                                                              \
      _Pragma("unroll") for (int m2 = 0; m2 < 4; ++m2) {                      \
        const int ab = ((MH) * 128 + wr * 64 + m2 * 16) * 32 + fro;           \
        afr[m2][0] = *reinterpret_cast<const bf16x8*>(&L[S][0][ab]);          \
        afr[m2][1] = *reinterpret_cast<const bf16x8*>(&L[S][1][ab]);          \
      }                                                                       \
    }                                                                         \
    if (LOADB) {                                                              \
      _Pragma("unroll") for (int n2 = 0; n2 < 2; ++n2) {                      \
        const int bb = ((NH) * 128 + wc * 32 + n2 * 16) * 32 + fro;           \
        bfr[(NH)][n2][0] = *reinterpret_cast<const bf16x8*>(&L[S][2][bb]);    \
        bfr[(NH)][n2][1] = *reinterpret_cast<const bf16x8*>(&L[S][3][bb]);    \
      }                                                                       \
    }                                                                         \
    STAGE_CODE;                                                               \
    WAIT_CODE;                                                                \
    __builtin_amdgcn_s_barrier();                                             \
    __builtin_amdgcn_s_setprio(1);                                            \
    _Pragma("unroll") for (int t = 0; t < 3; ++t)                             \
      _Pragma("unroll") for (int m2 = 0; m2 < 4; ++m2)                        \
        _Pragma("unroll") for (int n2 = 0; n2 < 2; ++n2) {                    \
          f32x4* ac = &acc[(MH) * 4 + m2][(NH) * 2 + n2];                     \
          *ac = __builtin_amdgcn_mfma_f32_16x16x32_bf16(afr[m2][t == 1],      \
                    bfr[(NH)][n2][t == 2], *ac, 0, 0, 0);                     \
        }                                                                     \
    __builtin_amdgcn_s_setprio(0);                                            \
    __builtin_amdgcn_s_barrier();                                             \
  }

#define V6 asm volatile("s_waitcnt vmcnt(6)" ::: "memory")
#define V0 asm volatile("s_waitcnt vmcnt(0)" ::: "memory")

  // TILE(U,S): 4 phases (mh,nh) = (0,0),(0,1),(1,1),(1,0); deep-stagger staging.
#define TILE(U, S)                                                            \
  PH(S, 0, 0, 1, 1,                                                           \
     { STAGE((U) + 1, (S) ^ 1, 0, 1); STAGE((U) + 1, (S) ^ 1, 1, 1); }, )     \
  PH(S, 0, 1, 0, 1,                                                           \
     { STAGE((U) + 2, (S), 0, 0); STAGE((U) + 2, (S), 1, 0); }, )             \
  PH(S, 1, 1, 1, 0,                                                           \
     { STAGE((U) + 2, (S), 2, 0); STAGE((U) + 2, (S), 3, 0); }, )             \
  PH(S, 1, 0, 0, 0,                                                           \
     { STAGE((U) + 2, (S), 2, 1); STAGE((U) + 2, (S), 3, 1); }, V6)

  // prologue: tile0 full + tile1 {aH0,bH0,bH1}; vmcnt(6) -> tile0 landed
  STAGE(0, 0, 0, 0); STAGE(0, 0, 1, 0);   // aH0(0)
  STAGE(0, 0, 2, 0); STAGE(0, 0, 3, 0);   // bH0(0)
  STAGE(0, 0, 2, 1); STAGE(0, 0, 3, 1);   // bH1(0)
  STAGE(0, 0, 0, 1); STAGE(0, 0, 1, 1);   // aH1(0)
  STAGE(1, 1, 0, 0); STAGE(1, 1, 1, 0);   // aH0(1)
  STAGE(1, 1, 2, 0); STAGE(1, 1, 3, 0);   // bH0(1)
  STAGE(1, 1, 2, 1); STAGE(1, 1, 3, 1);   // bH1(1)
  V6;
  __builtin_amdgcn_s_barrier();

  for (int u = 0; u < NT - 4; u += 2) {   // tiles 0..27
    TILE(u, 0)
    TILE(u + 1, 1)
  }
  TILE(NT - 4, 0)                          // tile 28 (stages into 29,30)
  TILE(NT - 3, 1)                          // tile 29 (stages into 30,31)
  // tile 30 (slot 0): only aH1(31) remains to stage; drain at ph3
  PH(0, 0, 0, 1, 1, { STAGE(31, 1, 0, 1); STAGE(31, 1, 1, 1); }, )
  PH(0, 0, 1, 0, 1, , )
  PH(0, 1, 1, 1, 0, , )
  PH(0, 1, 0, 0, 0, , V0)
  // tile 31 (slot 1): no staging, no waits
  PH(1, 0, 0, 1, 1, , )
  PH(1, 0, 1, 0, 1, , )
  PH(1, 1, 1, 1, 0, , )
  PH(1, 1, 0, 0, 0, , )

#undef TILE
#undef V6
#undef V0
#undef PH
#undef STAGE

  // ---------- fused quantized-LSTM epilogue ----------
  const int hb = bn * 4 + wc;
  const int h = hb * 16 + lr;
  float bias[4];
#pragma unroll
  for (int g = 0; g < 4; ++g)
    bias[g] = biasC[bn * 256 + ((g >> 1) * 8 + wc * 2 + (g & 1)) * 16 + lr];
#pragma unroll
  for (int mh = 0; mh < 2; ++mh) {
#pragma unroll
    for (int m2 = 0; m2 < 4; ++m2) {
      const int m = mh * 4 + m2;
#pragma unroll
      for (int r = 0; r < 4; ++r) {
        const int row = mbase + mh * 128 + wr * 64 + m2 * 16 + lg * 4 + r;
        const float gi = acc[m][0][r] + bias[0];
        const float gf = acc[m][1][r] + bias[1];
        const float gc = acc[m][2][r] + bias[2];
        const float go = acc[m][3][r] + bias[3];
        const float ig = fq_u(sigm(gi));
        const float fg = fq_u(sigm(gf));
        const float cg = fq_s(tanhf(gc));
        const float og = fq_u(sigm(go));
        const float cxv = cx[(size_t)row * HD + h];
        const float t1 = fq_s(fg * cxv);
        const float t2 = fq_s(ig * cg);
        const float cyv = fq_s((t1 + t2) * 0.5f);
        const float hyv = fq_s(og * fq_s(tanhf(cyv * 2.0f)));
        out[(size_t)row * HD + h] = hyv;
        out[HY_OFF + (size_t)row * HD + h] = cyv;
      }
    }
  }
}

// ---------- launch ----------
extern "C" void kernel_launch(void* const* d_in, const int* in_sizes, int n_in,
                              void* d_out, int out_size, void* d_ws, size_t ws_size,
                              hipStream_t stream) {
  const float* input = (const float*)d_in[0];
  const float* hx    = (const float*)d_in[1];
  const float* cx    = (const float*)d_in[2];
  const float* w_ih  = (const float*)d_in[3];
  const float* w_hh  = (const float*)d_in[4];
  const float* b_ih  = (const float*)d_in[5];
  const float* b_hh  = (const float*)d_in[6];
  const float* n_ih  = (const float*)d_in[7];
  const float* n_hh  = (const float*)d_in[8];
  const float* nb_ih = (const float*)d_in[9];
  const float* nb_hh = (const float*)d_in[10];
  float* out = (float*)d_out;

  char* ws = (char*)d_ws;
  float* maxes = (float*)ws;                                   // 16 B (+pad to 256)
  u16* Xhi = (u16*)(ws + 256);                                 // 16 MB
  u16* Xlo = (u16*)(ws + 256 + 16777216);                      // 16 MB
  u16* Whi = (u16*)(ws + 256 + 2 * 16777216);                  // 4 MB
  u16* Wlo = (u16*)(ws + 256 + 2 * 16777216 + 4194304);        // 4 MB
  float* biasC = (float*)(ws + 256 + 2 * 16777216 + 2 * 4194304); // 8 KB

  hipMemsetAsync(maxes, 0xFF, 16, stream);  // -NaN sentinel; atomic lattice fixes it
  hipLaunchKernelGGL(k_prep_max, dim3(2052), dim3(256), 0, stream,
                     w_ih, w_hh, b_ih, b_hh, maxes);
  hipLaunchKernelGGL(k_prep_build, dim3(2568), dim3(256), 0, stream,
                     input, hx, w_ih, w_hh, n_ih, n_hh, b_ih, b_hh,
                     nb_ih, nb_hh, maxes, Xhi, Xlo, Whi, Wlo, biasC);
  hipLaunchKernelGGL(k_gemm_lstm, dim3(256), dim3(512), 0, stream,
                     Xhi, Xlo, Whi, Wlo, biasC, cx, out);
}